// Round 1
// baseline (1201.049 us; speedup 1.0000x reference)
//
#include <hip/hip_runtime.h>
#include <hip/hip_bf16.h>
#include <hip/hip_cooperative_groups.h>

// LinearAttention collapse (all I/O fp32; x->bf16 only inside the MFMA GEMM):
//   out[b] = x[b] @ W_eff[b] + b_eff[b]
//   W_eff[b] = Wq@Wo + Wk@(diag(aw[b]) * (Wp@Wo))          [256 x 64]
//   b_eff[b] = (bq+bp)@Wo + bo + bk@(diag(aw[b])*(Wp@Wo))  [64]
//   aw[b]    = s_x[b]@Wq + t_sum[b]*bq                     [512]
//   s_x[b]   = sum_n t[b,n]*x[b,n,:],  t_sum[b] = sum_n t[b,n]
//   t[b,n]   = SCALE*(x[b,n].(Wq@qw) + bq.qw)
//
// R1: single cooperative kernel (3 grid.sync) replacing 4 dispatches.
//   - prep spread over 195 blocks (1 output/thread, wave-reduced bqq)
//   - phase B: 16-lane-group row reduce (4 shfl / 4 rows vs 6 shfl / row)
//   - phase D: stage W_effT once per TWO 64-row tiles
//   - LDS capped at 33792 B -> 4 blocks/CU -> 1024 blocks co-resident
//   - fallback: 4 plain launches if cooperative launch refused

#define NN 16384
#define CC 256
#define DD 512
#define HH 64
#define SCALE_F 0.125f
#define GRID_BLKS 1024
#define SMEM_BYTES 33792   // max(phaseD 64*264*2=33792, phaseC 19472, phaseA 8192)

// float-offset workspace layout (unchanged from previous version)
#define OFF_SX    0        // [8][256]
#define OFF_TSUM  2048     // [8]
#define OFF_WQQ   2056     // [256]
#define OFF_BQQ   2312     // [1]
#define OFF_WPWO  2320     // [512][64] fp32
#define OFF_WQWO  35088    // [256][64] fp32
#define OFF_CBIAS 51472    // [64]
#define OFF_BEFF  51536    // [8][64]
#define OFF_WEFFT 52048    // bf16 [8][64][256] (byte ofs 208192, 16B aligned)

typedef unsigned short ushort_t;
typedef __attribute__((ext_vector_type(8))) short short8;     // 8 bf16
typedef __attribute__((ext_vector_type(4))) float floatx4;

__device__ __forceinline__ unsigned short f2bf(float f) {
    __hip_bfloat16 h = __float2bfloat16(f);
    return __builtin_bit_cast(unsigned short, h);
}

// ---------------- Phase A: batch-independent weight folding + zero accums ----
__device__ __forceinline__ void phaseA(
    const float* __restrict__ Wq, const float* __restrict__ bq,
    const float* __restrict__ qw, const float* __restrict__ Wp,
    const float* __restrict__ bp, const float* __restrict__ Wo,
    const float* __restrict__ bo, float* __restrict__ ws,
    unsigned char* smem)
{
    const int tid = threadIdx.x;
    for (int vb = blockIdx.x; vb < 195; vb += gridDim.x) {
        if (vb < 128) {
            // WpWo rows d0..d0+3 : stage 4 rows of Wp, one output per thread
            float* lds = (float*)smem;
            const int d0 = vb * 4;
            for (int i = tid; i < 2048; i += 256) lds[i] = Wp[d0 * 512 + i];
            __syncthreads();
            const int dl = tid >> 6, h = tid & 63;
            float acc = 0.f;
            for (int e = 0; e < 512; ++e)
                acc = fmaf(lds[dl * 512 + e], Wo[e * 64 + h], acc);
            ws[OFF_WPWO + (d0 + dl) * 64 + h] = acc;
        } else if (vb < 192) {
            // WqWo rows c0..c0+3
            float* lds = (float*)smem;
            const int c0 = (vb - 128) * 4;
            for (int i = tid; i < 2048; i += 256) lds[i] = Wq[c0 * 512 + i];
            __syncthreads();
            const int cl = tid >> 6, h = tid & 63;
            float acc = 0.f;
            for (int e = 0; e < 512; ++e)
                acc = fmaf(lds[cl * 512 + e], Wo[e * 64 + h], acc);
            ws[OFF_WQWO + (c0 + cl) * 64 + h] = acc;
        } else if (vb == 192) {
            // wqq = Wq @ qw ; bqq = bq . qw (wave-reduced)
            float* lds = (float*)smem;            // qw: 512 floats
            float* lb  = (float*)(smem + 2048);   // scalar accumulator
            for (int i = tid; i < 512; i += 256) lds[i] = qw[i];
            if (tid == 0) *lb = 0.f;
            __syncthreads();
            const float* wr = Wq + tid * 512;
            float acc = 0.f;
            for (int d = 0; d < 512; ++d) acc = fmaf(wr[d], lds[d], acc);
            ws[OFF_WQQ + tid] = acc;
            float pb = fmaf(bq[tid], lds[tid], bq[tid + 256] * lds[tid + 256]);
#pragma unroll
            for (int m = 1; m < 64; m <<= 1) pb += __shfl_xor(pb, m);
            if ((tid & 63) == 0) atomicAdd(lb, pb);
            __syncthreads();
            if (tid == 0) ws[OFF_BQQ] = *lb;
        } else if (vb == 193) {
            // cbias[h] = (bq+bp)@Wo + bo
            if (tid < 64) {
                float acc = bo[tid];
                for (int d = 0; d < 512; ++d)
                    acc = fmaf(bq[d] + bp[d], Wo[d * 64 + tid], acc);
                ws[OFF_CBIAS + tid] = acc;
            }
        } else {
            // zero s_x + t_sum
            for (int i = tid; i < 2056; i += 256) ws[OFF_SX + i] = 0.f;
        }
        __syncthreads();
    }
}

// ---------------- Phase B: stream x, reduce s_x / t_sum -----------------------
// 16-lane groups: lane owns 16 cols (4x floatx4); 4 rows per wave-iteration;
// row-dot reduce = 4 shfl_xor (1,2,4,8) within the quad's 16 lanes.
__device__ __forceinline__ void phaseB(
    const float* __restrict__ x, float* __restrict__ ws, unsigned char* smem)
{
    const int tid  = threadIdx.x;
    const int lane = tid & 63;
    const int wave = tid >> 6;
    const int quad = lane >> 4;
    const int l15  = lane & 15;
    float* lacc  = (float*)smem;          // 256 floats
    float* ltsum = (float*)(smem + 1024);

    floatx4 wv[4];
#pragma unroll
    for (int j = 0; j < 4; ++j)
        wv[j] = *(const floatx4*)(ws + OFF_WQQ + j * 64 + l15 * 4);
    const float bqq = ws[OFF_BQQ];

    for (int vb = blockIdx.x; vb < 1024; vb += gridDim.x) {
        const int b = vb >> 7;
        const int rbase = (vb & 127) * 128;
        lacc[tid] = 0.f;
        if (tid == 0) *ltsum = 0.f;
        __syncthreads();

        const float* xb = x + (size_t)b * NN * CC;
        const int r0 = rbase + wave * 32 + quad;   // rows r0 + 4*it
        floatx4 accs[4];
#pragma unroll
        for (int j = 0; j < 4; ++j)
#pragma unroll
            for (int k = 0; k < 4; ++k) accs[j][k] = 0.f;
        float ts = 0.f;

#pragma unroll 2
        for (int it = 0; it < 8; ++it) {
            const float* xr = xb + (size_t)(r0 + it * 4) * CC + l15 * 4;
            const floatx4 x0 = *(const floatx4*)(xr);
            const floatx4 x1 = *(const floatx4*)(xr + 64);
            const floatx4 x2 = *(const floatx4*)(xr + 128);
            const floatx4 x3 = *(const floatx4*)(xr + 192);
            float p = 0.f;
#pragma unroll
            for (int k = 0; k < 4; ++k) {
                p = fmaf(x0[k], wv[0][k], p);
                p = fmaf(x1[k], wv[1][k], p);
                p = fmaf(x2[k], wv[2][k], p);
                p = fmaf(x3[k], wv[3][k], p);
            }
            p += __shfl_xor(p, 1);
            p += __shfl_xor(p, 2);
            p += __shfl_xor(p, 4);
            p += __shfl_xor(p, 8);
            const float t = SCALE_F * (p + bqq);
            ts += t;
#pragma unroll
            for (int k = 0; k < 4; ++k) {
                accs[0][k] = fmaf(t, x0[k], accs[0][k]);
                accs[1][k] = fmaf(t, x1[k], accs[1][k]);
                accs[2][k] = fmaf(t, x2[k], accs[2][k]);
                accs[3][k] = fmaf(t, x3[k], accs[3][k]);
            }
        }

        // cross-quad reduce (xor 16, 32), quad0 lanes accumulate into LDS
#pragma unroll
        for (int j = 0; j < 4; ++j)
#pragma unroll
            for (int k = 0; k < 4; ++k) {
                float v = accs[j][k];
                v += __shfl_xor(v, 16);
                v += __shfl_xor(v, 32);
                if (quad == 0) atomicAdd(&lacc[j * 64 + l15 * 4 + k], v);
            }
        if (l15 == 0) atomicAdd(ltsum, ts);
        __syncthreads();
        atomicAdd(&ws[OFF_SX + b * 256 + tid], lacc[tid]);
        if (tid == 0) atomicAdd(&ws[OFF_TSUM + b], *ltsum);
        __syncthreads();
    }
}

// ---------------- Phase C: aw -> W_effT (bf16) + b_eff -------------------------
__device__ __forceinline__ void phaseC(
    const float* __restrict__ Wq, const float* __restrict__ bq,
    const float* __restrict__ Wk, const float* __restrict__ bk,
    float* __restrict__ ws, unsigned char* smem)
{
    const int tid = threadIdx.x;
    for (int vb = blockIdx.x; vb < 64; vb += gridDim.x) {
        const int b = vb >> 3;
        const int c0 = (vb & 7) * 32;
        float* lsx = (float*)smem;             // 256
        float* law = (float*)(smem + 1024);    // 512
        float* lts = (float*)(smem + 3072);    // 1
        float* wpT = (float*)(smem + 3088);    // 64*64 fp32 = 16 KB tile

        lsx[tid] = ws[OFF_SX + b * 256 + tid];
        if (tid == 0) *lts = ws[OFF_TSUM + b];
        __syncthreads();
        const float tsum = *lts;

        // aw[d] = s_x @ Wq[:,d] + tsum*bq[d]
        for (int d = tid; d < 512; d += 256) {
            float acc = tsum * bq[d];
            for (int c = 0; c < 256; ++c) acc = fmaf(lsx[c], Wq[c * 512 + d], acc);
            law[d] = acc;
        }
        __syncthreads();

        // W_eff[c,h] = WqWo[c,h] + sum_d Wk[c,d]*aw[d]*WpWo[d,h]
        const int c = c0 + (tid >> 3);
        const int hb = (tid & 7) * 8;
        float acc[8];
#pragma unroll
        for (int j = 0; j < 8; ++j) acc[j] = ws[OFF_WQWO + c * 64 + hb + j];

        for (int t8 = 0; t8 < 8; ++t8) {
            const int d0 = t8 * 64;
            for (int i = tid; i < 4096; i += 256) wpT[i] = ws[OFF_WPWO + d0 * 64 + i];
            __syncthreads();
            for (int dl = 0; dl < 64; ++dl) {
                const float g = Wk[c * 512 + d0 + dl] * law[d0 + dl];
                const floatx4 p0 = *(const floatx4*)(wpT + dl * 64 + hb);
                const floatx4 p1 = *(const floatx4*)(wpT + dl * 64 + hb + 4);
                acc[0] = fmaf(g, p0[0], acc[0]); acc[1] = fmaf(g, p0[1], acc[1]);
                acc[2] = fmaf(g, p0[2], acc[2]); acc[3] = fmaf(g, p0[3], acc[3]);
                acc[4] = fmaf(g, p1[0], acc[4]); acc[5] = fmaf(g, p1[1], acc[5]);
                acc[6] = fmaf(g, p1[2], acc[6]); acc[7] = fmaf(g, p1[3], acc[7]);
            }
            __syncthreads();
        }

        ushort_t* wt = (ushort_t*)(ws + OFF_WEFFT) + (size_t)b * (HH * CC);
#pragma unroll
        for (int j = 0; j < 8; ++j)
            wt[(size_t)(hb + j) * CC + c] = f2bf(acc[j]);

        // b_eff once per batch; law persists in LDS
        if ((vb & 7) == 0 && tid < 64) {
            float a = ws[OFF_CBIAS + tid];
            for (int d = 0; d < 512; ++d)
                a = fmaf(bk[d] * law[d], ws[OFF_WPWO + d * 64 + tid], a);
            ws[OFF_BEFF + b * 64 + tid] = a;
        }
        __syncthreads();
    }
}

// ---------------- Phase D: out = x @ W_eff + b_eff  (MFMA bf16) ----------------
// Stage W_effT once, compute TWO 64-row tiles per block.
__device__ __forceinline__ void phaseD(
    const float* __restrict__ x, const float* __restrict__ ws,
    float* __restrict__ out, unsigned char* smem)
{
    const int tid  = threadIdx.x;
    const int lane = tid & 63;
    const int wave = tid >> 6;
    const int quad = lane >> 4;
    const int l15  = lane & 15;
    ushort_t* lwt = (ushort_t*)smem;   // 64 x 264 (pad 8) -> 33792 B

    for (int vb = blockIdx.x; vb < 1024; vb += gridDim.x) {
        const int b = vb >> 7;
        const int rt0 = vb & 127;
        const ushort_t* wt = (const ushort_t*)(ws + OFF_WEFFT) + (size_t)b * (HH * CC);
        for (int o = tid; o < 2048; o += 256) {
            const int h = o >> 5, seg = o & 31;
            *(short8*)(lwt + h * 264 + seg * 8) = *(const short8*)(wt + h * 256 + seg * 8);
        }
        __syncthreads();

        const float* beff = ws + OFF_BEFF + b * 64;
        float bias[4];
#pragma unroll
        for (int ht = 0; ht < 4; ++ht) bias[ht] = beff[ht * 16 + l15];

#pragma unroll
        for (int s = 0; s < 2; ++s) {
            const int row0 = (rt0 + s * 128) * 64 + wave * 16;
            const float* xr = x + ((size_t)b * NN + row0 + l15) * CC + quad * 8;
            short8 afrag[8];
#pragma unroll
            for (int kk = 0; kk < 8; ++kk) {
                const floatx4 u0 = *(const floatx4*)(xr + kk * 32);
                const floatx4 u1 = *(const floatx4*)(xr + kk * 32 + 4);
                short8 t;
                t[0] = (short)f2bf(u0[0]); t[1] = (short)f2bf(u0[1]);
                t[2] = (short)f2bf(u0[2]); t[3] = (short)f2bf(u0[3]);
                t[4] = (short)f2bf(u1[0]); t[5] = (short)f2bf(u1[1]);
                t[6] = (short)f2bf(u1[2]); t[7] = (short)f2bf(u1[3]);
                afrag[kk] = t;
            }
            floatx4 acc[4];
#pragma unroll
            for (int ht = 0; ht < 4; ++ht)
#pragma unroll
                for (int r = 0; r < 4; ++r) acc[ht][r] = 0.f;

#pragma unroll
            for (int kk = 0; kk < 8; ++kk)
#pragma unroll
                for (int ht = 0; ht < 4; ++ht) {
                    const short8 bf =
                        *(const short8*)(lwt + (ht * 16 + l15) * 264 + quad * 8 + kk * 32);
                    acc[ht] = __builtin_amdgcn_mfma_f32_16x16x32_bf16(
                        afrag[kk], bf, acc[ht], 0, 0, 0);
                }

            // D: col = lane&15 (h), row = quad*4 + reg
#pragma unroll
            for (int ht = 0; ht < 4; ++ht) {
                const int h = ht * 16 + l15;
#pragma unroll
                for (int r = 0; r < 4; ++r) {
                    const int row = row0 + quad * 4 + r;
                    out[((size_t)b * NN + row) * HH + h] = acc[ht][r] + bias[ht];
                }
            }
        }
        __syncthreads();
    }
}

// ---------------- fused cooperative kernel ------------------------------------
__global__ __launch_bounds__(256, 4) void k_fused(
    const float* __restrict__ x,  const float* __restrict__ Wq,
    const float* __restrict__ bq, const float* __restrict__ Wk,
    const float* __restrict__ bk, const float* __restrict__ qw,
    const float* __restrict__ Wp, const float* __restrict__ bp,
    const float* __restrict__ Wo, const float* __restrict__ bo,
    float* __restrict__ ws, float* __restrict__ out)
{
    __shared__ __align__(16) unsigned char smem[SMEM_BYTES];
    cooperative_groups::grid_group grid = cooperative_groups::this_grid();
    phaseA(Wq, bq, qw, Wp, bp, Wo, bo, ws, smem);
    grid.sync();
    phaseB(x, ws, smem);
    grid.sync();
    phaseC(Wq, bq, Wk, bk, ws, smem);
    grid.sync();
    phaseD(x, ws, out, smem);
}

// ---------------- non-cooperative fallback wrappers ---------------------------
__global__ __launch_bounds__(256, 4) void k_phA(
    const float* __restrict__ Wq, const float* __restrict__ bq,
    const float* __restrict__ qw, const float* __restrict__ Wp,
    const float* __restrict__ bp, const float* __restrict__ Wo,
    const float* __restrict__ bo, float* __restrict__ ws)
{
    __shared__ __align__(16) unsigned char smem[SMEM_BYTES];
    phaseA(Wq, bq, qw, Wp, bp, Wo, bo, ws, smem);
}
__global__ __launch_bounds__(256, 4) void k_phB(
    const float* __restrict__ x, float* __restrict__ ws)
{
    __shared__ __align__(16) unsigned char smem[SMEM_BYTES];
    phaseB(x, ws, smem);
}
__global__ __launch_bounds__(256, 4) void k_phC(
    const float* __restrict__ Wq, const float* __restrict__ bq,
    const float* __restrict__ Wk, const float* __restrict__ bk,
    float* __restrict__ ws)
{
    __shared__ __align__(16) unsigned char smem[SMEM_BYTES];
    phaseC(Wq, bq, Wk, bk, ws, smem);
}
__global__ __launch_bounds__(256, 4) void k_phD(
    const float* __restrict__ x, const float* __restrict__ ws,
    float* __restrict__ out)
{
    __shared__ __align__(16) unsigned char smem[SMEM_BYTES];
    phaseD(x, ws, out, smem);
}

extern "C" void kernel_launch(void* const* d_in, const int* in_sizes, int n_in,
                              void* d_out, int out_size, void* d_ws, size_t ws_size,
                              hipStream_t stream) {
    const float* x  = (const float*)d_in[0];
    const float* Wq = (const float*)d_in[1];
    const float* bq = (const float*)d_in[2];
    const float* Wk = (const float*)d_in[3];
    const float* bk = (const float*)d_in[4];
    const float* qw = (const float*)d_in[5];
    const float* Wp = (const float*)d_in[6];
    const float* bp = (const float*)d_in[7];
    const float* Wo = (const float*)d_in[8];
    const float* bo = (const float*)d_in[9];
    float* ws  = (float*)d_ws;
    float* out = (float*)d_out;

    void* args[12] = {
        (void*)&x,  (void*)&Wq, (void*)&bq, (void*)&Wk, (void*)&bk, (void*)&qw,
        (void*)&Wp, (void*)&bp, (void*)&Wo, (void*)&bo, (void*)&ws, (void*)&out};

    hipError_t err = hipLaunchCooperativeKernel(
        (void*)k_fused, dim3(GRID_BLKS), dim3(256), args, 0, stream);
    if (err != hipSuccess) {
        // fallback: 4 plain launches (same phase code, kernel-boundary sync)
        hipLaunchKernelGGL(k_phA, dim3(195),  dim3(256), 0, stream,
                           Wq, bq, qw, Wp, bp, Wo, bo, ws);
        hipLaunchKernelGGL(k_phB, dim3(1024), dim3(256), 0, stream, x, ws);
        hipLaunchKernelGGL(k_phC, dim3(64),   dim3(256), 0, stream,
                           Wq, bq, Wk, bk, ws);
        hipLaunchKernelGGL(k_phD, dim3(1024), dim3(256), 0, stream, x, ws, out);
    }
}

// Round 2
// 338.436 us; speedup vs baseline: 3.5488x; 3.5488x over previous
//
#include <hip/hip_runtime.h>
#include <hip/hip_bf16.h>

// LinearAttention collapse (all I/O fp32; x->bf16 only inside the MFMA GEMM):
//   out[b] = x[b] @ W_eff[b] + b_eff[b]
//   W_eff[b] = Wq@Wo + Wk@(diag(aw[b]) * (Wp@Wo))          [256 x 64]
//   b_eff[b] = (bq+bp)@Wo + bo + bk@(diag(aw[b])*(Wp@Wo))  [64]
//   aw[b]    = s_x[b]@Wq + t_sum[b]*bq                     [512]
//   s_x[b]   = sum_n t[b,n]*x[b,n,:],  t_sum[b] = sum_n t[b,n]
//   t[b,n]   = SCALE*(x[b,n].(Wq@qw) + bq.qw)
//
// R2: revert cooperative fusion (grid.sync = device-scope L2 flush + spin ->
//     571 GB/s, 2% VALU, 1050us). Keep phase-level wins as 4 plain kernels:
//   - prep over 195 blocks, 1 output/thread, wave-reduced bqq
//   - phase B: 16-lane-group reduce (4 shfl / 4 rows), 4x16B loads in flight
//   - phase D: stage W_effT once per TWO 64-row tiles
//   - no min-waves launch_bounds clamp (VGPR freedom for MLP)

#define NN 16384
#define CC 256
#define DD 512
#define HH 64
#define SCALE_F 0.125f

// float-offset workspace layout
#define OFF_SX    0        // [8][256]
#define OFF_TSUM  2048     // [8]
#define OFF_WQQ   2056     // [256]
#define OFF_BQQ   2312     // [1]
#define OFF_WPWO  2320     // [512][64] fp32
#define OFF_WQWO  35088    // [256][64] fp32
#define OFF_CBIAS 51472    // [64]
#define OFF_BEFF  51536    // [8][64]
#define OFF_WEFFT 52048    // bf16 [8][64][256] (byte ofs 208192, 16B aligned)

typedef unsigned short ushort_t;
typedef __attribute__((ext_vector_type(8))) short short8;     // 8 bf16
typedef __attribute__((ext_vector_type(4))) float floatx4;

__device__ __forceinline__ unsigned short f2bf(float f) {
    __hip_bfloat16 h = __float2bfloat16(f);
    return __builtin_bit_cast(unsigned short, h);
}

// ---------------- K0: batch-independent weight folding + zero accumulators ----
// grid 195: 0..127 WpWo (4 rows ea), 128..191 WqWo (4 rows ea),
//           192 wqq/bqq, 193 cbias, 194 zero s_x/t_sum
__global__ __launch_bounds__(256) void k_prep(
    const float* __restrict__ Wq, const float* __restrict__ bq,
    const float* __restrict__ qw, const float* __restrict__ Wp,
    const float* __restrict__ bp, const float* __restrict__ Wo,
    const float* __restrict__ bo, float* __restrict__ ws)
{
    __shared__ float lds[2056];
    const int tid = threadIdx.x;
    const int bid = blockIdx.x;

    if (bid < 128) {
        // WpWo rows d0..d0+3 : stage 4 rows of Wp, one output per thread
        const int d0 = bid * 4;
        for (int i = tid; i < 2048; i += 256) lds[i] = Wp[d0 * 512 + i];
        __syncthreads();
        const int dl = tid >> 6, h = tid & 63;
        float acc = 0.f;
        for (int e = 0; e < 512; ++e)
            acc = fmaf(lds[dl * 512 + e], Wo[e * 64 + h], acc);
        ws[OFF_WPWO + (d0 + dl) * 64 + h] = acc;
    } else if (bid < 192) {
        // WqWo rows c0..c0+3
        const int c0 = (bid - 128) * 4;
        for (int i = tid; i < 2048; i += 256) lds[i] = Wq[c0 * 512 + i];
        __syncthreads();
        const int cl = tid >> 6, h = tid & 63;
        float acc = 0.f;
        for (int e = 0; e < 512; ++e)
            acc = fmaf(lds[cl * 512 + e], Wo[e * 64 + h], acc);
        ws[OFF_WQWO + (c0 + cl) * 64 + h] = acc;
    } else if (bid == 192) {
        // wqq = Wq @ qw ; bqq = bq . qw (wave-reduced)
        float* lb = lds + 2048;
        for (int i = tid; i < 512; i += 256) lds[i] = qw[i];
        if (tid == 0) *lb = 0.f;
        __syncthreads();
        const float* wr = Wq + tid * 512;
        float acc = 0.f;
        for (int d = 0; d < 512; ++d) acc = fmaf(wr[d], lds[d], acc);
        ws[OFF_WQQ + tid] = acc;
        float pb = fmaf(bq[tid], lds[tid], bq[tid + 256] * lds[tid + 256]);
#pragma unroll
        for (int m = 1; m < 64; m <<= 1) pb += __shfl_xor(pb, m);
        if ((tid & 63) == 0) atomicAdd(lb, pb);
        __syncthreads();
        if (tid == 0) ws[OFF_BQQ] = *lb;
    } else if (bid == 193) {
        // cbias[h] = (bq+bp)@Wo + bo ; 4 partials per h, LDS-reduced
        const int h = tid & 63, part = tid >> 6;
        float acc = 0.f;
        for (int d = part * 128; d < part * 128 + 128; ++d)
            acc = fmaf(bq[d] + bp[d], Wo[d * 64 + h], acc);
        lds[part * 64 + h] = acc;
        __syncthreads();
        if (tid < 64)
            ws[OFF_CBIAS + tid] = bo[tid] + lds[tid] + lds[64 + tid] +
                                  lds[128 + tid] + lds[192 + tid];
    } else {
        // zero s_x + t_sum
        for (int i = tid; i < 2056; i += 256) ws[OFF_SX + i] = 0.f;
    }
}

// ---------------- K1: stream x, reduce s_x / t_sum -----------------------
// 16-lane groups: lane owns 16 cols (4x floatx4); 4 rows per wave-iteration;
// row-dot reduce = 4 shfl_xor (1,2,4,8) within the quad's 16 lanes.
__global__ __launch_bounds__(256) void k_phase1(
    const float* __restrict__ x, float* __restrict__ ws)
{
    const int tid  = threadIdx.x;
    const int lane = tid & 63;
    const int wave = tid >> 6;
    const int quad = lane >> 4;
    const int l15  = lane & 15;
    __shared__ float lacc[256];
    __shared__ float ltsum;

    floatx4 wv[4];
#pragma unroll
    for (int j = 0; j < 4; ++j)
        wv[j] = *(const floatx4*)(ws + OFF_WQQ + j * 64 + l15 * 4);
    const float bqq = ws[OFF_BQQ];

    const int vb = blockIdx.x;
    const int b = vb >> 7;
    const int rbase = (vb & 127) * 128;
    lacc[tid] = 0.f;
    if (tid == 0) ltsum = 0.f;
    __syncthreads();

    const float* xb = x + (size_t)b * NN * CC;
    const int r0 = rbase + wave * 32 + quad;   // rows r0 + 4*it
    floatx4 accs[4];
#pragma unroll
    for (int j = 0; j < 4; ++j)
#pragma unroll
        for (int k = 0; k < 4; ++k) accs[j][k] = 0.f;
    float ts = 0.f;

#pragma unroll 2
    for (int it = 0; it < 8; ++it) {
        const float* xr = xb + (size_t)(r0 + it * 4) * CC + l15 * 4;
        const floatx4 x0 = *(const floatx4*)(xr);
        const floatx4 x1 = *(const floatx4*)(xr + 64);
        const floatx4 x2 = *(const floatx4*)(xr + 128);
        const floatx4 x3 = *(const floatx4*)(xr + 192);
        float p = 0.f;
#pragma unroll
        for (int k = 0; k < 4; ++k) {
            p = fmaf(x0[k], wv[0][k], p);
            p = fmaf(x1[k], wv[1][k], p);
            p = fmaf(x2[k], wv[2][k], p);
            p = fmaf(x3[k], wv[3][k], p);
        }
        p += __shfl_xor(p, 1);
        p += __shfl_xor(p, 2);
        p += __shfl_xor(p, 4);
        p += __shfl_xor(p, 8);
        const float t = SCALE_F * (p + bqq);
        ts += t;
#pragma unroll
        for (int k = 0; k < 4; ++k) {
            accs[0][k] = fmaf(t, x0[k], accs[0][k]);
            accs[1][k] = fmaf(t, x1[k], accs[1][k]);
            accs[2][k] = fmaf(t, x2[k], accs[2][k]);
            accs[3][k] = fmaf(t, x3[k], accs[3][k]);
        }
    }

    // cross-quad reduce (xor 16, 32), quad0 lanes accumulate into LDS
#pragma unroll
    for (int j = 0; j < 4; ++j)
#pragma unroll
        for (int k = 0; k < 4; ++k) {
            float v = accs[j][k];
            v += __shfl_xor(v, 16);
            v += __shfl_xor(v, 32);
            if (quad == 0) atomicAdd(&lacc[j * 64 + l15 * 4 + k], v);
        }
    if (l15 == 0) atomicAdd(&ltsum, ts);
    __syncthreads();
    atomicAdd(&ws[OFF_SX + b * 256 + tid], lacc[tid]);
    if (tid == 0) atomicAdd(&ws[OFF_TSUM + b], ltsum);
}

// ---------------- K2: aw -> W_effT (bf16) + b_eff -------------------------
// grid 64: vb>>3 = batch, (vb&7)*32 = c-tile
__global__ __launch_bounds__(256) void k_weff(
    const float* __restrict__ Wq, const float* __restrict__ bq,
    const float* __restrict__ Wk, const float* __restrict__ bk,
    float* __restrict__ ws)
{
    const int tid = threadIdx.x;
    const int vb = blockIdx.x;
    const int b = vb >> 3;
    const int c0 = (vb & 7) * 32;
    __shared__ float lsx[256];
    __shared__ float law[512];
    __shared__ float lts;
    __shared__ float wpT[64 * 64];   // 16 KB tile of WpWo

    lsx[tid] = ws[OFF_SX + b * 256 + tid];
    if (tid == 0) lts = ws[OFF_TSUM + b];
    __syncthreads();
    const float tsum = lts;

    // aw[d] = s_x @ Wq[:,d] + tsum*bq[d]   (coalesced over d)
    for (int d = tid; d < 512; d += 256) {
        float acc = tsum * bq[d];
        for (int c = 0; c < 256; ++c) acc = fmaf(lsx[c], Wq[c * 512 + d], acc);
        law[d] = acc;
    }
    __syncthreads();

    // W_eff[c,h] = WqWo[c,h] + sum_d Wk[c,d]*aw[d]*WpWo[d,h]
    const int c = c0 + (tid >> 3);
    const int hb = (tid & 7) * 8;
    float acc[8];
#pragma unroll
    for (int j = 0; j < 8; ++j) acc[j] = ws[OFF_WQWO + c * 64 + hb + j];

    for (int t8 = 0; t8 < 8; ++t8) {
        const int d0 = t8 * 64;
        for (int i = tid; i < 4096; i += 256) wpT[i] = ws[OFF_WPWO + d0 * 64 + i];
        __syncthreads();
        for (int dl = 0; dl < 64; ++dl) {
            const float g = Wk[c * 512 + d0 + dl] * law[d0 + dl];
            const floatx4 p0 = *(const floatx4*)(wpT + dl * 64 + hb);
            const floatx4 p1 = *(const floatx4*)(wpT + dl * 64 + hb + 4);
            acc[0] = fmaf(g, p0[0], acc[0]); acc[1] = fmaf(g, p0[1], acc[1]);
            acc[2] = fmaf(g, p0[2], acc[2]); acc[3] = fmaf(g, p0[3], acc[3]);
            acc[4] = fmaf(g, p1[0], acc[4]); acc[5] = fmaf(g, p1[1], acc[5]);
            acc[6] = fmaf(g, p1[2], acc[6]); acc[7] = fmaf(g, p1[3], acc[7]);
        }
        __syncthreads();
    }

    ushort_t* wt = (ushort_t*)(ws + OFF_WEFFT) + (size_t)b * (HH * CC);
#pragma unroll
    for (int j = 0; j < 8; ++j)
        wt[(size_t)(hb + j) * CC + c] = f2bf(acc[j]);

    // b_eff (once per batch); law persists in LDS
    if ((vb & 7) == 0 && tid < 64) {
        float a = ws[OFF_CBIAS + tid];
        for (int d = 0; d < 512; ++d)
            a = fmaf(bk[d] * law[d], ws[OFF_WPWO + d * 64 + tid], a);
        ws[OFF_BEFF + b * 64 + tid] = a;
    }
}

// ---------------- K3: out = x @ W_eff + b_eff  (MFMA bf16) -----------------
// grid 1024: vb>>7 = batch, vb&127 = row-tile base; each block computes
// TWO 64-row tiles (rt0 and rt0+128) per single W_effT staging.
__global__ __launch_bounds__(256) void k_out(
    const float* __restrict__ x, const float* __restrict__ ws,
    float* __restrict__ out)
{
    const int tid  = threadIdx.x;
    const int lane = tid & 63;
    const int wave = tid >> 6;
    const int quad = lane >> 4;
    const int l15  = lane & 15;
    // Stage W_effT[b] in LDS, stride 264 (pad 8) -> 2-way-free ds_read_b128
    __shared__ __align__(16) ushort_t lwt[64 * 264];

    const int vb = blockIdx.x;
    const int b = vb >> 7;
    const int rt0 = vb & 127;
    const ushort_t* wt = (const ushort_t*)(ws + OFF_WEFFT) + (size_t)b * (HH * CC);
    for (int o = tid; o < 2048; o += 256) {
        const int h = o >> 5, seg = o & 31;
        *(short8*)(lwt + h * 264 + seg * 8) = *(const short8*)(wt + h * 256 + seg * 8);
    }
    __syncthreads();

    const float* beff = ws + OFF_BEFF + b * 64;
    float bias[4];
#pragma unroll
    for (int ht = 0; ht < 4; ++ht) bias[ht] = beff[ht * 16 + l15];

#pragma unroll
    for (int s = 0; s < 2; ++s) {
        const int row0 = (rt0 + s * 128) * 64 + wave * 16;
        const float* xr = x + ((size_t)b * NN + row0 + l15) * CC + quad * 8;
        short8 afrag[8];
#pragma unroll
        for (int kk = 0; kk < 8; ++kk) {
            const floatx4 u0 = *(const floatx4*)(xr + kk * 32);
            const floatx4 u1 = *(const floatx4*)(xr + kk * 32 + 4);
            short8 t;
            t[0] = (short)f2bf(u0[0]); t[1] = (short)f2bf(u0[1]);
            t[2] = (short)f2bf(u0[2]); t[3] = (short)f2bf(u0[3]);
            t[4] = (short)f2bf(u1[0]); t[5] = (short)f2bf(u1[1]);
            t[6] = (short)f2bf(u1[2]); t[7] = (short)f2bf(u1[3]);
            afrag[kk] = t;
        }
        floatx4 acc[4];
#pragma unroll
        for (int ht = 0; ht < 4; ++ht)
#pragma unroll
            for (int r = 0; r < 4; ++r) acc[ht][r] = 0.f;

#pragma unroll
        for (int kk = 0; kk < 8; ++kk)
#pragma unroll
            for (int ht = 0; ht < 4; ++ht) {
                const short8 bf =
                    *(const short8*)(lwt + (ht * 16 + l15) * 264 + quad * 8 + kk * 32);
                acc[ht] = __builtin_amdgcn_mfma_f32_16x16x32_bf16(
                    afrag[kk], bf, acc[ht], 0, 0, 0);
            }

        // D: col = lane&15 (h within tile), row = quad*4 + reg
#pragma unroll
        for (int ht = 0; ht < 4; ++ht) {
            const int h = ht * 16 + l15;
#pragma unroll
            for (int r = 0; r < 4; ++r) {
                const int row = row0 + quad * 4 + r;
                out[((size_t)b * NN + row) * HH + h] = acc[ht][r] + bias[ht];
            }
        }
    }
}

extern "C" void kernel_launch(void* const* d_in, const int* in_sizes, int n_in,
                              void* d_out, int out_size, void* d_ws, size_t ws_size,
                              hipStream_t stream) {
    const float* x  = (const float*)d_in[0];
    const float* Wq = (const float*)d_in[1];
    const float* bq = (const float*)d_in[2];
    const float* Wk = (const float*)d_in[3];
    const float* bk = (const float*)d_in[4];
    const float* qw = (const float*)d_in[5];
    const float* Wp = (const float*)d_in[6];
    const float* bp = (const float*)d_in[7];
    const float* Wo = (const float*)d_in[8];
    const float* bo = (const float*)d_in[9];
    float* ws  = (float*)d_ws;
    float* out = (float*)d_out;

    hipLaunchKernelGGL(k_prep,   dim3(195),  dim3(256), 0, stream,
                       Wq, bq, qw, Wp, bp, Wo, bo, ws);
    hipLaunchKernelGGL(k_phase1, dim3(1024), dim3(256), 0, stream, x, ws);
    hipLaunchKernelGGL(k_weff,   dim3(64),   dim3(256), 0, stream,
                       Wq, bq, Wk, bk, ws);
    hipLaunchKernelGGL(k_out,    dim3(1024), dim3(256), 0, stream, x, ws, out);
}

// Round 3
// 308.223 us; speedup vs baseline: 3.8967x; 1.0980x over previous
//
#include <hip/hip_runtime.h>
#include <hip/hip_bf16.h>

// LinearAttention collapse (all I/O fp32; x->bf16 only inside the MFMA GEMM):
//   out[b] = x[b] @ W_eff[b] + b_eff[b]
//   W_eff[b] = Wq@Wo + Wk@(diag(aw[b]) * (Wp@Wo))          [256 x 64]
//   b_eff[b] = (bq+bp)@Wo + bo + bk@(diag(aw[b])*(Wp@Wo))  [64]
//   aw[b]    = s_x[b]@Wq + t_sum[b]*bq                     [512]
//   s_x[b]   = sum_n t[b,n]*x[b,n,:],  t_sum[b] = sum_n t[b,n]
//   t[b,n]   = SCALE*(x[b,n].(Wq@qw) + bq.qw)
//
// R3: k_weff was the bottleneck (135us, 2.5% occupancy, 1.2% VALU -> pure
//     latency stall at 64 blocks). Rebuilt for TLP:
//   - grid (64,8) = 512 blocks, 1 output/thread (c=c0+tid>>6, h=tid&63)
//   - no LDS tiling / no barriers in main loop: WpWo read as coalesced
//     256B wave-lines (L2-hot), Wk*aw wave-uniform broadcast
//   - 4-way split accumulators (128-long dep chains instead of 512)
//   - aw recomputed per block (L2-hot Wq, trivial FLOPs); b_eff uses all
//     256 threads (4x128-d partials + LDS reduce)
// k_prep / k_phase1 / k_out unchanged from R2 (proven).

#define NN 16384
#define CC 256
#define DD 512
#define HH 64
#define SCALE_F 0.125f

// float-offset workspace layout
#define OFF_SX    0        // [8][256]
#define OFF_TSUM  2048     // [8]
#define OFF_WQQ   2056     // [256]
#define OFF_BQQ   2312     // [1]
#define OFF_WPWO  2320     // [512][64] fp32
#define OFF_WQWO  35088    // [256][64] fp32
#define OFF_CBIAS 51472    // [64]
#define OFF_BEFF  51536    // [8][64]
#define OFF_WEFFT 52048    // bf16 [8][64][256] (byte ofs 208192, 16B aligned)

typedef unsigned short ushort_t;
typedef __attribute__((ext_vector_type(8))) short short8;     // 8 bf16
typedef __attribute__((ext_vector_type(4))) float floatx4;

__device__ __forceinline__ unsigned short f2bf(float f) {
    __hip_bfloat16 h = __float2bfloat16(f);
    return __builtin_bit_cast(unsigned short, h);
}

// ---------------- K0: batch-independent weight folding + zero accumulators ----
// grid 195: 0..127 WpWo (4 rows ea), 128..191 WqWo (4 rows ea),
//           192 wqq/bqq, 193 cbias, 194 zero s_x/t_sum
__global__ __launch_bounds__(256) void k_prep(
    const float* __restrict__ Wq, const float* __restrict__ bq,
    const float* __restrict__ qw, const float* __restrict__ Wp,
    const float* __restrict__ bp, const float* __restrict__ Wo,
    const float* __restrict__ bo, float* __restrict__ ws)
{
    __shared__ float lds[2056];
    const int tid = threadIdx.x;
    const int bid = blockIdx.x;

    if (bid < 128) {
        // WpWo rows d0..d0+3 : stage 4 rows of Wp, one output per thread
        const int d0 = bid * 4;
        for (int i = tid; i < 2048; i += 256) lds[i] = Wp[d0 * 512 + i];
        __syncthreads();
        const int dl = tid >> 6, h = tid & 63;
        float acc = 0.f;
        for (int e = 0; e < 512; ++e)
            acc = fmaf(lds[dl * 512 + e], Wo[e * 64 + h], acc);
        ws[OFF_WPWO + (d0 + dl) * 64 + h] = acc;
    } else if (bid < 192) {
        // WqWo rows c0..c0+3
        const int c0 = (bid - 128) * 4;
        for (int i = tid; i < 2048; i += 256) lds[i] = Wq[c0 * 512 + i];
        __syncthreads();
        const int cl = tid >> 6, h = tid & 63;
        float acc = 0.f;
        for (int e = 0; e < 512; ++e)
            acc = fmaf(lds[cl * 512 + e], Wo[e * 64 + h], acc);
        ws[OFF_WQWO + (c0 + cl) * 64 + h] = acc;
    } else if (bid == 192) {
        // wqq = Wq @ qw ; bqq = bq . qw (wave-reduced)
        float* lb = lds + 2048;
        for (int i = tid; i < 512; i += 256) lds[i] = qw[i];
        if (tid == 0) *lb = 0.f;
        __syncthreads();
        const float* wr = Wq + tid * 512;
        float acc = 0.f;
        for (int d = 0; d < 512; ++d) acc = fmaf(wr[d], lds[d], acc);
        ws[OFF_WQQ + tid] = acc;
        float pb = fmaf(bq[tid], lds[tid], bq[tid + 256] * lds[tid + 256]);
#pragma unroll
        for (int m = 1; m < 64; m <<= 1) pb += __shfl_xor(pb, m);
        if ((tid & 63) == 0) atomicAdd(lb, pb);
        __syncthreads();
        if (tid == 0) ws[OFF_BQQ] = *lb;
    } else if (bid == 193) {
        // cbias[h] = (bq+bp)@Wo + bo ; 4 partials per h, LDS-reduced
        const int h = tid & 63, part = tid >> 6;
        float acc = 0.f;
        for (int d = part * 128; d < part * 128 + 128; ++d)
            acc = fmaf(bq[d] + bp[d], Wo[d * 64 + h], acc);
        lds[part * 64 + h] = acc;
        __syncthreads();
        if (tid < 64)
            ws[OFF_CBIAS + tid] = bo[tid] + lds[tid] + lds[64 + tid] +
                                  lds[128 + tid] + lds[192 + tid];
    } else {
        // zero s_x + t_sum
        for (int i = tid; i < 2056; i += 256) ws[OFF_SX + i] = 0.f;
    }
}

// ---------------- K1: stream x, reduce s_x / t_sum -----------------------
// 16-lane groups: lane owns 16 cols (4x floatx4); 4 rows per wave-iteration;
// row-dot reduce = 4 shfl_xor (1,2,4,8) within the quad's 16 lanes.
__global__ __launch_bounds__(256) void k_phase1(
    const float* __restrict__ x, float* __restrict__ ws)
{
    const int tid  = threadIdx.x;
    const int lane = tid & 63;
    const int wave = tid >> 6;
    const int quad = lane >> 4;
    const int l15  = lane & 15;
    __shared__ float lacc[256];
    __shared__ float ltsum;

    floatx4 wv[4];
#pragma unroll
    for (int j = 0; j < 4; ++j)
        wv[j] = *(const floatx4*)(ws + OFF_WQQ + j * 64 + l15 * 4);
    const float bqq = ws[OFF_BQQ];

    const int vb = blockIdx.x;
    const int b = vb >> 7;
    const int rbase = (vb & 127) * 128;
    lacc[tid] = 0.f;
    if (tid == 0) ltsum = 0.f;
    __syncthreads();

    const float* xb = x + (size_t)b * NN * CC;
    const int r0 = rbase + wave * 32 + quad;   // rows r0 + 4*it
    floatx4 accs[4];
#pragma unroll
    for (int j = 0; j < 4; ++j)
#pragma unroll
        for (int k = 0; k < 4; ++k) accs[j][k] = 0.f;
    float ts = 0.f;

#pragma unroll 2
    for (int it = 0; it < 8; ++it) {
        const float* xr = xb + (size_t)(r0 + it * 4) * CC + l15 * 4;
        const floatx4 x0 = *(const floatx4*)(xr);
        const floatx4 x1 = *(const floatx4*)(xr + 64);
        const floatx4 x2 = *(const floatx4*)(xr + 128);
        const floatx4 x3 = *(const floatx4*)(xr + 192);
        float p = 0.f;
#pragma unroll
        for (int k = 0; k < 4; ++k) {
            p = fmaf(x0[k], wv[0][k], p);
            p = fmaf(x1[k], wv[1][k], p);
            p = fmaf(x2[k], wv[2][k], p);
            p = fmaf(x3[k], wv[3][k], p);
        }
        p += __shfl_xor(p, 1);
        p += __shfl_xor(p, 2);
        p += __shfl_xor(p, 4);
        p += __shfl_xor(p, 8);
        const float t = SCALE_F * (p + bqq);
        ts += t;
#pragma unroll
        for (int k = 0; k < 4; ++k) {
            accs[0][k] = fmaf(t, x0[k], accs[0][k]);
            accs[1][k] = fmaf(t, x1[k], accs[1][k]);
            accs[2][k] = fmaf(t, x2[k], accs[2][k]);
            accs[3][k] = fmaf(t, x3[k], accs[3][k]);
        }
    }

    // cross-quad reduce (xor 16, 32), quad0 lanes accumulate into LDS
#pragma unroll
    for (int j = 0; j < 4; ++j)
#pragma unroll
        for (int k = 0; k < 4; ++k) {
            float v = accs[j][k];
            v += __shfl_xor(v, 16);
            v += __shfl_xor(v, 32);
            if (quad == 0) atomicAdd(&lacc[j * 64 + l15 * 4 + k], v);
        }
    if (l15 == 0) atomicAdd(&ltsum, ts);
    __syncthreads();
    atomicAdd(&ws[OFF_SX + b * 256 + tid], lacc[tid]);
    if (tid == 0) atomicAdd(&ws[OFF_TSUM + b], ltsum);
}

// ---------------- K2: aw -> W_effT (bf16) + b_eff -------------------------
// grid (64, 8): blockIdx.y = batch, blockIdx.x*4 = c-base.
// One output per thread (c = c0 + tid>>6, h = tid&63); no main-loop barriers.
__global__ __launch_bounds__(256) void k_weff(
    const float* __restrict__ Wq, const float* __restrict__ bq,
    const float* __restrict__ Wk, const float* __restrict__ bk,
    float* __restrict__ ws)
{
    const int tid = threadIdx.x;
    const int b = blockIdx.y;
    const int c0 = blockIdx.x * 4;
    __shared__ float lsx[256];
    __shared__ float law[512];
    __shared__ float lred[256];
    __shared__ float lts;

    lsx[tid] = ws[OFF_SX + b * 256 + tid];
    if (tid == 0) lts = ws[OFF_TSUM + b];
    __syncthreads();
    const float tsum = lts;

    // aw[d] = s_x @ Wq[:,d] + tsum*bq[d] ; 2 d's per thread, 4 partial chains
    for (int d = tid; d < 512; d += 256) {
        float a0 = 0.f, a1 = 0.f, a2 = 0.f, a3 = 0.f;
        for (int c = 0; c < 256; c += 4) {
            a0 = fmaf(lsx[c + 0], Wq[(c + 0) * 512 + d], a0);
            a1 = fmaf(lsx[c + 1], Wq[(c + 1) * 512 + d], a1);
            a2 = fmaf(lsx[c + 2], Wq[(c + 2) * 512 + d], a2);
            a3 = fmaf(lsx[c + 3], Wq[(c + 3) * 512 + d], a3);
        }
        law[d] = tsum * bq[d] + ((a0 + a1) + (a2 + a3));
    }
    __syncthreads();

    // W_eff[c,h] = WqWo[c,h] + sum_d Wk[c,d]*aw[d]*WpWo[d,h]
    // wave-uniform c -> Wk/law broadcast; WpWo rows are coalesced 256B lines
    const int cl = tid >> 6, h = tid & 63;
    const int c = c0 + cl;
    const float* wkr = Wk + (size_t)c * 512;
    const float* wp  = ws + OFF_WPWO;
    float a0 = 0.f, a1 = 0.f, a2 = 0.f, a3 = 0.f;
    for (int d = 0; d < 512; d += 4) {
        a0 = fmaf(wkr[d + 0] * law[d + 0], wp[(d + 0) * 64 + h], a0);
        a1 = fmaf(wkr[d + 1] * law[d + 1], wp[(d + 1) * 64 + h], a1);
        a2 = fmaf(wkr[d + 2] * law[d + 2], wp[(d + 2) * 64 + h], a2);
        a3 = fmaf(wkr[d + 3] * law[d + 3], wp[(d + 3) * 64 + h], a3);
    }
    const float acc = ws[OFF_WQWO + c * 64 + h] + ((a0 + a1) + (a2 + a3));

    ushort_t* wt = (ushort_t*)(ws + OFF_WEFFT) + (size_t)b * (HH * CC);
    wt[(size_t)h * CC + c] = f2bf(acc);

    // b_eff (one block per batch): 4x128-d partials across all 256 threads
    if (blockIdx.x == 0) {
        const int part = tid >> 6;
        float a = 0.f;
        for (int d = part * 128; d < part * 128 + 128; ++d)
            a = fmaf(bk[d] * law[d], wp[d * 64 + h], a);
        lred[tid] = a;
        __syncthreads();
        if (tid < 64)
            ws[OFF_BEFF + b * 64 + tid] = ws[OFF_CBIAS + tid] + lred[tid] +
                lred[64 + tid] + lred[128 + tid] + lred[192 + tid];
    }
}

// ---------------- K3: out = x @ W_eff + b_eff  (MFMA bf16) -----------------
// grid 1024: vb>>7 = batch, vb&127 = row-tile base; each block computes
// TWO 64-row tiles (rt0 and rt0+128) per single W_effT staging.
__global__ __launch_bounds__(256) void k_out(
    const float* __restrict__ x, const float* __restrict__ ws,
    float* __restrict__ out)
{
    const int tid  = threadIdx.x;
    const int lane = tid & 63;
    const int wave = tid >> 6;
    const int quad = lane >> 4;
    const int l15  = lane & 15;
    // Stage W_effT[b] in LDS, stride 264 (pad 8) -> 2-way-free ds_read_b128
    __shared__ __align__(16) ushort_t lwt[64 * 264];

    const int vb = blockIdx.x;
    const int b = vb >> 7;
    const int rt0 = vb & 127;
    const ushort_t* wt = (const ushort_t*)(ws + OFF_WEFFT) + (size_t)b * (HH * CC);
    for (int o = tid; o < 2048; o += 256) {
        const int h = o >> 5, seg = o & 31;
        *(short8*)(lwt + h * 264 + seg * 8) = *(const short8*)(wt + h * 256 + seg * 8);
    }
    __syncthreads();

    const float* beff = ws + OFF_BEFF + b * 64;
    float bias[4];
#pragma unroll
    for (int ht = 0; ht < 4; ++ht) bias[ht] = beff[ht * 16 + l15];

#pragma unroll
    for (int s = 0; s < 2; ++s) {
        const int row0 = (rt0 + s * 128) * 64 + wave * 16;
        const float* xr = x + ((size_t)b * NN + row0 + l15) * CC + quad * 8;
        short8 afrag[8];
#pragma unroll
        for (int kk = 0; kk < 8; ++kk) {
            const floatx4 u0 = *(const floatx4*)(xr + kk * 32);
            const floatx4 u1 = *(const floatx4*)(xr + kk * 32 + 4);
            short8 t;
            t[0] = (short)f2bf(u0[0]); t[1] = (short)f2bf(u0[1]);
            t[2] = (short)f2bf(u0[2]); t[3] = (short)f2bf(u0[3]);
            t[4] = (short)f2bf(u1[0]); t[5] = (short)f2bf(u1[1]);
            t[6] = (short)f2bf(u1[2]); t[7] = (short)f2bf(u1[3]);
            afrag[kk] = t;
        }
        floatx4 acc[4];
#pragma unroll
        for (int ht = 0; ht < 4; ++ht)
#pragma unroll
            for (int r = 0; r < 4; ++r) acc[ht][r] = 0.f;

#pragma unroll
        for (int kk = 0; kk < 8; ++kk)
#pragma unroll
            for (int ht = 0; ht < 4; ++ht) {
                const short8 bf =
                    *(const short8*)(lwt + (ht * 16 + l15) * 264 + quad * 8 + kk * 32);
                acc[ht] = __builtin_amdgcn_mfma_f32_16x16x32_bf16(
                    afrag[kk], bf, acc[ht], 0, 0, 0);
            }

        // D: col = lane&15 (h within tile), row = quad*4 + reg
#pragma unroll
        for (int ht = 0; ht < 4; ++ht) {
            const int h = ht * 16 + l15;
#pragma unroll
            for (int r = 0; r < 4; ++r) {
                const int row = row0 + quad * 4 + r;
                out[((size_t)b * NN + row) * HH + h] = acc[ht][r] + bias[ht];
            }
        }
    }
}

extern "C" void kernel_launch(void* const* d_in, const int* in_sizes, int n_in,
                              void* d_out, int out_size, void* d_ws, size_t ws_size,
                              hipStream_t stream) {
    const float* x  = (const float*)d_in[0];
    const float* Wq = (const float*)d_in[1];
    const float* bq = (const float*)d_in[2];
    const float* Wk = (const float*)d_in[3];
    const float* bk = (const float*)d_in[4];
    const float* qw = (const float*)d_in[5];
    const float* Wp = (const float*)d_in[6];
    const float* bp = (const float*)d_in[7];
    const float* Wo = (const float*)d_in[8];
    const float* bo = (const float*)d_in[9];
    float* ws  = (float*)d_ws;
    float* out = (float*)d_out;

    hipLaunchKernelGGL(k_prep,   dim3(195),    dim3(256), 0, stream,
                       Wq, bq, qw, Wp, bp, Wo, bo, ws);
    hipLaunchKernelGGL(k_phase1, dim3(1024),   dim3(256), 0, stream, x, ws);
    hipLaunchKernelGGL(k_weff,   dim3(64, 8),  dim3(256), 0, stream,
                       Wq, bq, Wk, bk, ws);
    hipLaunchKernelGGL(k_out,    dim3(1024),   dim3(256), 0, stream, x, ws, out);
}

// Round 4
// 301.299 us; speedup vs baseline: 3.9862x; 1.0230x over previous
//
#include <hip/hip_runtime.h>
#include <hip/hip_bf16.h>

// LinearAttention collapse (all I/O fp32; x->bf16 only inside the MFMA GEMM):
//   out[b] = x[b] @ W_eff[b] + b_eff[b]
//   W_eff[b] = Wq@Wo + Wk@(diag(aw[b]) * (Wp@Wo))          [256 x 64]
//   b_eff[b] = (bq+bp)@Wo + bo + bk@(diag(aw[b])*(Wp@Wo))  [64]
//   aw[b]    = s_x[b]@Wq + t_sum[b]*bq                     [512]
//   s_x[b]   = sum_n t[b,n]*x[b,n,:],  t_sum[b] = sum_n t[b,n]
//   t[b,n]   = SCALE*(x[b,n].(Wq@qw) + bq.qw)
//
// R4: k_weff still suspected dominant (~60-75us hiding under the 78us fills):
//     512 blocks EACH recomputed aw = 268 MB of L2 Wq traffic + 256-deep
//     dependent prologue per block. Fix:
//   - NEW k_aw (grid (2,8)): aw computed once per batch -> ws[OFF_AW]
//   - k_weff v3: no aw recompute, no LDS/barriers in main path; wave-uniform
//     Wk/aw broadcast + one coalesced WpWo line per d
//   - k_out: s=0 A-fragments loaded+converted BEFORE the staging barrier
//     (HBM latency hides under LDS staging; s=1 loads overlap s=0 MFMA)
// k_prep / k_phase1 unchanged (proven).

#define NN 16384
#define CC 256
#define DD 512
#define HH 64
#define SCALE_F 0.125f

// float-offset workspace layout
#define OFF_SX    0        // [8][256]
#define OFF_TSUM  2048     // [8]
#define OFF_WQQ   2056     // [256]
#define OFF_BQQ   2312     // [1]
#define OFF_WPWO  2320     // [512][64] fp32
#define OFF_WQWO  35088    // [256][64] fp32
#define OFF_CBIAS 51472    // [64]
#define OFF_BEFF  51536    // [8][64]
#define OFF_WEFFT 52048    // bf16 [8][64][256] (byte ofs 208192, 16B aligned)
#define OFF_AW    117584   // [8][512] fp32

typedef unsigned short ushort_t;
typedef __attribute__((ext_vector_type(8))) short short8;     // 8 bf16
typedef __attribute__((ext_vector_type(4))) float floatx4;

__device__ __forceinline__ unsigned short f2bf(float f) {
    __hip_bfloat16 h = __float2bfloat16(f);
    return __builtin_bit_cast(unsigned short, h);
}

// ---------------- K0: batch-independent weight folding + zero accumulators ----
// grid 195: 0..127 WpWo (4 rows ea), 128..191 WqWo (4 rows ea),
//           192 wqq/bqq, 193 cbias, 194 zero s_x/t_sum
__global__ __launch_bounds__(256) void k_prep(
    const float* __restrict__ Wq, const float* __restrict__ bq,
    const float* __restrict__ qw, const float* __restrict__ Wp,
    const float* __restrict__ bp, const float* __restrict__ Wo,
    const float* __restrict__ bo, float* __restrict__ ws)
{
    __shared__ float lds[2056];
    const int tid = threadIdx.x;
    const int bid = blockIdx.x;

    if (bid < 128) {
        // WpWo rows d0..d0+3 : stage 4 rows of Wp, one output per thread
        const int d0 = bid * 4;
        for (int i = tid; i < 2048; i += 256) lds[i] = Wp[d0 * 512 + i];
        __syncthreads();
        const int dl = tid >> 6, h = tid & 63;
        float acc = 0.f;
        for (int e = 0; e < 512; ++e)
            acc = fmaf(lds[dl * 512 + e], Wo[e * 64 + h], acc);
        ws[OFF_WPWO + (d0 + dl) * 64 + h] = acc;
    } else if (bid < 192) {
        // WqWo rows c0..c0+3
        const int c0 = (bid - 128) * 4;
        for (int i = tid; i < 2048; i += 256) lds[i] = Wq[c0 * 512 + i];
        __syncthreads();
        const int cl = tid >> 6, h = tid & 63;
        float acc = 0.f;
        for (int e = 0; e < 512; ++e)
            acc = fmaf(lds[cl * 512 + e], Wo[e * 64 + h], acc);
        ws[OFF_WQWO + (c0 + cl) * 64 + h] = acc;
    } else if (bid == 192) {
        // wqq = Wq @ qw ; bqq = bq . qw (wave-reduced)
        float* lb = lds + 2048;
        for (int i = tid; i < 512; i += 256) lds[i] = qw[i];
        if (tid == 0) *lb = 0.f;
        __syncthreads();
        const float* wr = Wq + tid * 512;
        float acc = 0.f;
        for (int d = 0; d < 512; ++d) acc = fmaf(wr[d], lds[d], acc);
        ws[OFF_WQQ + tid] = acc;
        float pb = fmaf(bq[tid], lds[tid], bq[tid + 256] * lds[tid + 256]);
#pragma unroll
        for (int m = 1; m < 64; m <<= 1) pb += __shfl_xor(pb, m);
        if ((tid & 63) == 0) atomicAdd(lb, pb);
        __syncthreads();
        if (tid == 0) ws[OFF_BQQ] = *lb;
    } else if (bid == 193) {
        // cbias[h] = (bq+bp)@Wo + bo ; 4 partials per h, LDS-reduced
        const int h = tid & 63, part = tid >> 6;
        float acc = 0.f;
        for (int d = part * 128; d < part * 128 + 128; ++d)
            acc = fmaf(bq[d] + bp[d], Wo[d * 64 + h], acc);
        lds[part * 64 + h] = acc;
        __syncthreads();
        if (tid < 64)
            ws[OFF_CBIAS + tid] = bo[tid] + lds[tid] + lds[64 + tid] +
                                  lds[128 + tid] + lds[192 + tid];
    } else {
        // zero s_x + t_sum
        for (int i = tid; i < 2056; i += 256) ws[OFF_SX + i] = 0.f;
    }
}

// ---------------- K1: stream x, reduce s_x / t_sum -----------------------
// 16-lane groups: lane owns 16 cols (4x floatx4); 4 rows per wave-iteration;
// row-dot reduce = 4 shfl_xor (1,2,4,8) within the quad's 16 lanes.
__global__ __launch_bounds__(256) void k_phase1(
    const float* __restrict__ x, float* __restrict__ ws)
{
    const int tid  = threadIdx.x;
    const int lane = tid & 63;
    const int wave = tid >> 6;
    const int quad = lane >> 4;
    const int l15  = lane & 15;
    __shared__ float lacc[256];
    __shared__ float ltsum;

    floatx4 wv[4];
#pragma unroll
    for (int j = 0; j < 4; ++j)
        wv[j] = *(const floatx4*)(ws + OFF_WQQ + j * 64 + l15 * 4);
    const float bqq = ws[OFF_BQQ];

    const int vb = blockIdx.x;
    const int b = vb >> 7;
    const int rbase = (vb & 127) * 128;
    lacc[tid] = 0.f;
    if (tid == 0) ltsum = 0.f;
    __syncthreads();

    const float* xb = x + (size_t)b * NN * CC;
    const int r0 = rbase + wave * 32 + quad;   // rows r0 + 4*it
    floatx4 accs[4];
#pragma unroll
    for (int j = 0; j < 4; ++j)
#pragma unroll
        for (int k = 0; k < 4; ++k) accs[j][k] = 0.f;
    float ts = 0.f;

#pragma unroll 2
    for (int it = 0; it < 8; ++it) {
        const float* xr = xb + (size_t)(r0 + it * 4) * CC + l15 * 4;
        const floatx4 x0 = *(const floatx4*)(xr);
        const floatx4 x1 = *(const floatx4*)(xr + 64);
        const floatx4 x2 = *(const floatx4*)(xr + 128);
        const floatx4 x3 = *(const floatx4*)(xr + 192);
        float p = 0.f;
#pragma unroll
        for (int k = 0; k < 4; ++k) {
            p = fmaf(x0[k], wv[0][k], p);
            p = fmaf(x1[k], wv[1][k], p);
            p = fmaf(x2[k], wv[2][k], p);
            p = fmaf(x3[k], wv[3][k], p);
        }
        p += __shfl_xor(p, 1);
        p += __shfl_xor(p, 2);
        p += __shfl_xor(p, 4);
        p += __shfl_xor(p, 8);
        const float t = SCALE_F * (p + bqq);
        ts += t;
#pragma unroll
        for (int k = 0; k < 4; ++k) {
            accs[0][k] = fmaf(t, x0[k], accs[0][k]);
            accs[1][k] = fmaf(t, x1[k], accs[1][k]);
            accs[2][k] = fmaf(t, x2[k], accs[2][k]);
            accs[3][k] = fmaf(t, x3[k], accs[3][k]);
        }
    }

    // cross-quad reduce (xor 16, 32), quad0 lanes accumulate into LDS
#pragma unroll
    for (int j = 0; j < 4; ++j)
#pragma unroll
        for (int k = 0; k < 4; ++k) {
            float v = accs[j][k];
            v += __shfl_xor(v, 16);
            v += __shfl_xor(v, 32);
            if (quad == 0) atomicAdd(&lacc[j * 64 + l15 * 4 + k], v);
        }
    if (l15 == 0) atomicAdd(&ltsum, ts);
    __syncthreads();
    atomicAdd(&ws[OFF_SX + b * 256 + tid], lacc[tid]);
    if (tid == 0) atomicAdd(&ws[OFF_TSUM + b], ltsum);
}

// ---------------- K2a: aw[b,d] = s_x[b]@Wq[:,d] + tsum[b]*bq[d] ------------
// grid (2, 8): blockIdx.y = batch, blockIdx.x = d-half. One d per thread;
// 8-way split accumulator chains for memory-level parallelism.
__global__ __launch_bounds__(256) void k_aw(
    const float* __restrict__ Wq, const float* __restrict__ bq,
    float* __restrict__ ws)
{
    const int tid = threadIdx.x;
    const int b = blockIdx.y;
    const int d = blockIdx.x * 256 + tid;
    __shared__ float lsx[256];
    __shared__ float lts;
    lsx[tid] = ws[OFF_SX + b * 256 + tid];
    if (tid == 0) lts = ws[OFF_TSUM + b];
    __syncthreads();

    float a[8];
#pragma unroll
    for (int j = 0; j < 8; ++j) a[j] = 0.f;
    for (int c = 0; c < 256; c += 8) {
#pragma unroll
        for (int j = 0; j < 8; ++j)
            a[j] = fmaf(lsx[c + j], Wq[(c + j) * 512 + d], a[j]);
    }
    const float s = ((a[0] + a[1]) + (a[2] + a[3])) +
                    ((a[4] + a[5]) + (a[6] + a[7]));
    ws[OFF_AW + b * 512 + d] = lts * bq[d] + s;
}

// ---------------- K2b: W_effT (bf16) + b_eff -------------------------------
// grid (64, 8): blockIdx.y = batch, blockIdx.x*4 = c-base.
// One output per thread (c = c0 + tid>>6, h = tid&63). Main path: no LDS,
// no barriers; Wk[c,d]*aw[d] wave-uniform, WpWo one coalesced line per d.
__global__ __launch_bounds__(256) void k_weff(
    const float* __restrict__ Wk, const float* __restrict__ bk,
    float* __restrict__ ws)
{
    const int tid = threadIdx.x;
    const int b = blockIdx.y;
    const int c0 = blockIdx.x * 4;
    __shared__ float lred[256];

    const int cl = tid >> 6, h = tid & 63;
    const int c = c0 + cl;
    const float* law = ws + OFF_AW + (size_t)b * 512;
    const float* wkr = Wk + (size_t)c * 512;
    const float* wp  = ws + OFF_WPWO;

    float a0 = 0.f, a1 = 0.f, a2 = 0.f, a3 = 0.f;
    for (int d = 0; d < 512; d += 4) {
        a0 = fmaf(wkr[d + 0] * law[d + 0], wp[(d + 0) * 64 + h], a0);
        a1 = fmaf(wkr[d + 1] * law[d + 1], wp[(d + 1) * 64 + h], a1);
        a2 = fmaf(wkr[d + 2] * law[d + 2], wp[(d + 2) * 64 + h], a2);
        a3 = fmaf(wkr[d + 3] * law[d + 3], wp[(d + 3) * 64 + h], a3);
    }
    const float acc = ws[OFF_WQWO + c * 64 + h] + ((a0 + a1) + (a2 + a3));

    ushort_t* wt = (ushort_t*)(ws + OFF_WEFFT) + (size_t)b * (HH * CC);
    wt[(size_t)h * CC + c] = f2bf(acc);

    // b_eff (one block per batch): 4x128-d partials across all 256 threads
    if (blockIdx.x == 0) {
        const int part = tid >> 6;
        float a = 0.f;
        for (int d = part * 128; d < part * 128 + 128; ++d)
            a = fmaf(bk[d] * law[d], wp[d * 64 + h], a);
        lred[tid] = a;
        __syncthreads();
        if (tid < 64)
            ws[OFF_BEFF + b * 64 + tid] = ws[OFF_CBIAS + tid] + lred[tid] +
                lred[64 + tid] + lred[128 + tid] + lred[192 + tid];
    }
}

// ---------------- K3: out = x @ W_eff + b_eff  (MFMA bf16) -----------------
// grid 1024: vb>>7 = batch, vb&127 = row-tile base; each block computes
// TWO 64-row tiles per single W_effT staging. s=0 A-fragments are loaded
// and converted BEFORE the staging barrier (global loads have no LDS dep,
// so their HBM latency hides under the LDS staging).
__global__ __launch_bounds__(256) void k_out(
    const float* __restrict__ x, const float* __restrict__ ws,
    float* __restrict__ out)
{
    const int tid  = threadIdx.x;
    const int lane = tid & 63;
    const int wave = tid >> 6;
    const int quad = lane >> 4;
    const int l15  = lane & 15;
    // Stage W_effT[b] in LDS, stride 264 (pad 8) -> 2-way-free ds_read_b128
    __shared__ __align__(16) ushort_t lwt[64 * 264];

    const int vb = blockIdx.x;
    const int b = vb >> 7;
    const int rt0 = vb & 127;

    // ---- s=0 A-fragments first (no LDS dependency) ----
    const int row0_0 = rt0 * 64 + wave * 16;
    const float* xr0 = x + ((size_t)b * NN + row0_0 + l15) * CC + quad * 8;
    short8 afrag0[8];
#pragma unroll
    for (int kk = 0; kk < 8; ++kk) {
        const floatx4 u0 = *(const floatx4*)(xr0 + kk * 32);
        const floatx4 u1 = *(const floatx4*)(xr0 + kk * 32 + 4);
        short8 t;
        t[0] = (short)f2bf(u0[0]); t[1] = (short)f2bf(u0[1]);
        t[2] = (short)f2bf(u0[2]); t[3] = (short)f2bf(u0[3]);
        t[4] = (short)f2bf(u1[0]); t[5] = (short)f2bf(u1[1]);
        t[6] = (short)f2bf(u1[2]); t[7] = (short)f2bf(u1[3]);
        afrag0[kk] = t;
    }

    // ---- stage W_effT ----
    const ushort_t* wt = (const ushort_t*)(ws + OFF_WEFFT) + (size_t)b * (HH * CC);
    for (int o = tid; o < 2048; o += 256) {
        const int h = o >> 5, seg = o & 31;
        *(short8*)(lwt + h * 264 + seg * 8) = *(const short8*)(wt + h * 256 + seg * 8);
    }
    __syncthreads();

    const float* beff = ws + OFF_BEFF + b * 64;
    float bias[4];
#pragma unroll
    for (int ht = 0; ht < 4; ++ht) bias[ht] = beff[ht * 16 + l15];

    // ---- s=0 MFMA + store ----
    {
        floatx4 acc[4];
#pragma unroll
        for (int ht = 0; ht < 4; ++ht)
#pragma unroll
            for (int r = 0; r < 4; ++r) acc[ht][r] = 0.f;
#pragma unroll
        for (int kk = 0; kk < 8; ++kk)
#pragma unroll
            for (int ht = 0; ht < 4; ++ht) {
                const short8 bf =
                    *(const short8*)(lwt + (ht * 16 + l15) * 264 + quad * 8 + kk * 32);
                acc[ht] = __builtin_amdgcn_mfma_f32_16x16x32_bf16(
                    afrag0[kk], bf, acc[ht], 0, 0, 0);
            }
#pragma unroll
        for (int ht = 0; ht < 4; ++ht) {
            const int h = ht * 16 + l15;
#pragma unroll
            for (int r = 0; r < 4; ++r) {
                const int row = row0_0 + quad * 4 + r;
                out[((size_t)b * NN + row) * HH + h] = acc[ht][r] + bias[ht];
            }
        }
    }

    // ---- s=1: load, convert, MFMA, store (overlaps s=0 MFMA via scheduler) --
    {
        const int row0_1 = (rt0 + 128) * 64 + wave * 16;
        const float* xr1 = x + ((size_t)b * NN + row0_1 + l15) * CC + quad * 8;
        short8 afrag1[8];
#pragma unroll
        for (int kk = 0; kk < 8; ++kk) {
            const floatx4 u0 = *(const floatx4*)(xr1 + kk * 32);
            const floatx4 u1 = *(const floatx4*)(xr1 + kk * 32 + 4);
            short8 t;
            t[0] = (short)f2bf(u0[0]); t[1] = (short)f2bf(u0[1]);
            t[2] = (short)f2bf(u0[2]); t[3] = (short)f2bf(u0[3]);
            t[4] = (short)f2bf(u1[0]); t[5] = (short)f2bf(u1[1]);
            t[6] = (short)f2bf(u1[2]); t[7] = (short)f2bf(u1[3]);
            afrag1[kk] = t;
        }
        floatx4 acc[4];
#pragma unroll
        for (int ht = 0; ht < 4; ++ht)
#pragma unroll
            for (int r = 0; r < 4; ++r) acc[ht][r] = 0.f;
#pragma unroll
        for (int kk = 0; kk < 8; ++kk)
#pragma unroll
            for (int ht = 0; ht < 4; ++ht) {
                const short8 bf =
                    *(const short8*)(lwt + (ht * 16 + l15) * 264 + quad * 8 + kk * 32);
                acc[ht] = __builtin_amdgcn_mfma_f32_16x16x32_bf16(
                    afrag1[kk], bf, acc[ht], 0, 0, 0);
            }
#pragma unroll
        for (int ht = 0; ht < 4; ++ht) {
            const int h = ht * 16 + l15;
#pragma unroll
            for (int r = 0; r < 4; ++r) {
                const int row = row0_1 + quad * 4 + r;
                out[((size_t)b * NN + row) * HH + h] = acc[ht][r] + bias[ht];
            }
        }
    }
}

extern "C" void kernel_launch(void* const* d_in, const int* in_sizes, int n_in,
                              void* d_out, int out_size, void* d_ws, size_t ws_size,
                              hipStream_t stream) {
    const float* x  = (const float*)d_in[0];
    const float* Wq = (const float*)d_in[1];
    const float* bq = (const float*)d_in[2];
    const float* Wk = (const float*)d_in[3];
    const float* bk = (const float*)d_in[4];
    const float* qw = (const float*)d_in[5];
    const float* Wp = (const float*)d_in[6];
    const float* bp = (const float*)d_in[7];
    const float* Wo = (const float*)d_in[8];
    const float* bo = (const float*)d_in[9];
    float* ws  = (float*)d_ws;
    float* out = (float*)d_out;

    hipLaunchKernelGGL(k_prep,   dim3(195),    dim3(256), 0, stream,
                       Wq, bq, qw, Wp, bp, Wo, bo, ws);
    hipLaunchKernelGGL(k_phase1, dim3(1024),   dim3(256), 0, stream, x, ws);
    hipLaunchKernelGGL(k_aw,     dim3(2, 8),   dim3(256), 0, stream, Wq, bq, ws);
    hipLaunchKernelGGL(k_weff,   dim3(64, 8),  dim3(256), 0, stream, Wk, bk, ws);
    hipLaunchKernelGGL(k_out,    dim3(1024),   dim3(256), 0, stream, x, ws, out);
}